// Round 1
// baseline (94.834 us; speedup 1.0000x reference)
//
#include <hip/hip_runtime.h>

// VQ2D nearest-code assignment, N=16.7M points, K=4 codes, 2-D.
// Outputs concatenated flat (float32): [q_grad N*2][idx N][q N*2].
// q_grad forward value == q (STE), idx written as float.
// Pure streaming: ~470 MB traffic -> HBM-bound, target ~75-90 us.

__global__ __launch_bounds__(256) void VQ2D_26938034881022_kernel(
    const float* __restrict__ z,      // [N,2]
    const float* __restrict__ cb,     // [4,2]
    float* __restrict__ out,          // [5N]
    long long npairs,                 // N/2 (each iter handles 2 points)
    long long N)
{
    // Codebook -> registers (8 floats, L1-broadcast read).
    float cx0 = cb[0], cy0 = cb[1];
    float cx1 = cb[2], cy1 = cb[3];
    float cx2 = cb[4], cy2 = cb[5];
    float cx3 = cb[6], cy3 = cb[7];

    float* __restrict__ out_qg  = out;          // N*2 floats
    float* __restrict__ out_idx = out + 2 * N;  // N floats
    float* __restrict__ out_q   = out + 3 * N;  // N*2 floats

    const float4* __restrict__ z4 = reinterpret_cast<const float4*>(z);
    float4* __restrict__ qg4 = reinterpret_cast<float4*>(out_qg);
    float4* __restrict__ q4  = reinterpret_cast<float4*>(out_q);
    float2* __restrict__ id2 = reinterpret_cast<float2*>(out_idx);

    long long stride = (long long)gridDim.x * blockDim.x;
    for (long long t = (long long)blockIdx.x * blockDim.x + threadIdx.x;
         t < npairs; t += stride) {
        float4 zz = z4[t];  // point A = (x,y), point B = (z,w)

        // --- point A argmin over 4 codes; select-chain, no indexed array ---
        float dxa = zz.x - cx0, dya = zz.y - cy0;
        float ba = dxa * dxa + dya * dya;
        float qax = cx0, qay = cy0, fia = 0.0f;
        {
            float dx = zz.x - cx1, dy = zz.y - cy1;
            float d = dx * dx + dy * dy;
            if (d < ba) { ba = d; qax = cx1; qay = cy1; fia = 1.0f; }
        }
        {
            float dx = zz.x - cx2, dy = zz.y - cy2;
            float d = dx * dx + dy * dy;
            if (d < ba) { ba = d; qax = cx2; qay = cy2; fia = 2.0f; }
        }
        {
            float dx = zz.x - cx3, dy = zz.y - cy3;
            float d = dx * dx + dy * dy;
            if (d < ba) { ba = d; qax = cx3; qay = cy3; fia = 3.0f; }
        }

        // --- point B ---
        float dxb = zz.z - cx0, dyb = zz.w - cy0;
        float bb = dxb * dxb + dyb * dyb;
        float qbx = cx0, qby = cy0, fib = 0.0f;
        {
            float dx = zz.z - cx1, dy = zz.w - cy1;
            float d = dx * dx + dy * dy;
            if (d < bb) { bb = d; qbx = cx1; qby = cy1; fib = 1.0f; }
        }
        {
            float dx = zz.z - cx2, dy = zz.w - cy2;
            float d = dx * dx + dy * dy;
            if (d < bb) { bb = d; qbx = cx2; qby = cy2; fib = 2.0f; }
        }
        {
            float dx = zz.z - cx3, dy = zz.w - cy3;
            float d = dx * dx + dy * dy;
            if (d < bb) { bb = d; qbx = cx3; qby = cy3; fib = 3.0f; }
        }

        float4 q;
        q.x = qax; q.y = qay; q.z = qbx; q.w = qby;
        qg4[t] = q;
        q4[t]  = q;
        float2 fi;
        fi.x = fia; fi.y = fib;
        id2[t] = fi;
    }
}

extern "C" void kernel_launch(void* const* d_in, const int* in_sizes, int n_in,
                              void* d_out, int out_size, void* d_ws, size_t ws_size,
                              hipStream_t stream) {
    const float* z  = (const float*)d_in[0];
    const float* cb = (const float*)d_in[1];
    float* out = (float*)d_out;

    long long N = (long long)in_sizes[0] / 2;  // in_sizes[0] = N*2
    long long npairs = N / 2;                  // N = 16,777,216 -> even

    int block = 256;
    long long want = (npairs + block - 1) / block;
    int grid = (int)(want < 2048 ? want : 2048);

    VQ2D_26938034881022_kernel<<<grid, block, 0, stream>>>(z, cb, out, npairs, N);
}